// Round 1
// baseline (842.626 us; speedup 1.0000x reference)
//
#include <hip/hip_runtime.h>
#include <math.h>

// ---------------------------------------------------------------------------
// Kernel A: feats_x = leaky_relu(dense_feats @ w_unary1 + b, 0.1)   [N,32]
//           guidance_x = feats_x @ w_gu + b_gu                      [N,32]
// 8 points per 256-thread block; 32 threads per point (one per channel).
// ---------------------------------------------------------------------------
__global__ __launch_bounds__(256) void feats_kernel(
    const float* __restrict__ df,
    const float* __restrict__ w1, const float* __restrict__ b1,
    const float* __restrict__ wg, const float* __restrict__ bg,
    float* __restrict__ fx, float* __restrict__ gx, int N)
{
    __shared__ float sW1[64][32];
    __shared__ float sWg[32][32];
    __shared__ float sIn[8][64];
    __shared__ float sFx[8][33];
    int t = threadIdx.x;
    for (int i = t; i < 64 * 32; i += 256) ((float*)sW1)[i] = w1[i];
    for (int i = t; i < 32 * 32; i += 256) ((float*)sWg)[i] = wg[i];
    int p = t >> 5, c = t & 31;
    long n0 = (long)blockIdx.x * 8 + p;
    bool ok = n0 < (long)N;
    float in0 = 0.f, in1 = 0.f;
    if (ok) { in0 = df[n0 * 64 + c]; in1 = df[n0 * 64 + 32 + c]; }
    sIn[p][c] = in0;
    sIn[p][c + 32] = in1;
    __syncthreads();
    float acc = b1[c];
#pragma unroll
    for (int i = 0; i < 64; i++) acc += sIn[p][i] * sW1[i][c];
    acc = acc > 0.f ? acc : 0.1f * acc;   // LeakyReLU(0.1)
    sFx[p][c] = acc;
    __syncthreads();
    float g = bg[c];
#pragma unroll
    for (int i = 0; i < 32; i++) g += sFx[p][i] * sWg[i][c];
    if (ok) { fx[n0 * 32 + c] = acc; gx[n0 * 32 + c] = g; }
}

// ---------------------------------------------------------------------------
// Kernel B: per-sparse-point pipeline. 16 points / 256-thread block.
// thread t -> (p = t>>4 point-in-tile, q = t&15 neighbor index).
// p-groups are 16 consecutive lanes => shfl_xor(1,2,4,8) reduces over k.
// ---------------------------------------------------------------------------
struct SmemU {
    union {
        struct { float nf[16][16][36]; float w3[16][16][16]; } a;
        float agg[16][512];
    };
};

__global__ __launch_bounds__(256) void pcf_kernel(
    const float* __restrict__ vi, const int* __restrict__ nei,
    const float* __restrict__ df,
    const float* __restrict__ fx, const float* __restrict__ gx,
    const float* __restrict__ wpe, const float* __restrict__ bpe,
    const float* __restrict__ wg1, const float* __restrict__ bg1,
    const float* __restrict__ wg2, const float* __restrict__ bg2,
    const float* __restrict__ wn1, const float* __restrict__ bn1,
    const float* __restrict__ wn2, const float* __restrict__ bn2,
    const float* __restrict__ wn3, const float* __restrict__ bn3,
    const float* __restrict__ wlin, const float* __restrict__ blin,
    const float* __restrict__ wu2, const float* __restrict__ bu2,
    const float* __restrict__ wsc, const float* __restrict__ bsc,
    float* __restrict__ out, int M)
{
    __shared__ SmemU U;
    __shared__ float sOut64[16][64];
    __shared__ float sSf[16][64];
    __shared__ int sInd[16][16];

    int t = threadIdx.x;
    int p = t >> 4, q = t & 15;
    long m = (long)blockIdx.x * 16 + p;
    bool okm = m < (long)M;
    int ind = 0;
    if (okm) ind = nei[m * 16 + q];
    sInd[p][q] = ind;

    // ---------------- phase 1: per-(point, neighbor) ----------------
    float v[12];
    {
        const float4* v4 = (const float4*)(vi + (okm ? (m * 16 + q) * 12 : 0));
        float4 a = v4[0], b = v4[1], c = v4[2];
        v[0] = a.x; v[1] = a.y; v[2] = a.z; v[3] = a.w;
        v[4] = b.x; v[5] = b.y; v[6] = b.z; v[7] = b.w;
        v[8] = c.x; v[9] = c.y; v[10] = c.z; v[11] = c.w;
    }
    // positional encoding: relu(vi @ w_pe + b_pe) -> pe[32]
    float pe[32];
#pragma unroll
    for (int c = 0; c < 32; c++) {
        float a = bpe[c];
#pragma unroll
        for (int i = 0; i < 12; i++) a += v[i] * wpe[i * 32 + c];
        pe[c] = fmaxf(a, 0.f);
    }
    // gather guidance row
    float gd[32];
    {
        const float4* g4 = (const float4*)(gx + (long)ind * 32);
#pragma unroll
        for (int c8 = 0; c8 < 8; c8++) {
            float4 gg = g4[c8];
            gd[c8 * 4 + 0] = gg.x; gd[c8 * 4 + 1] = gg.y;
            gd[c8 * 4 + 2] = gg.z; gd[c8 * 4 + 3] = gg.w;
        }
    }
    // scores = (g_feat - colmax_k(g_feat)) @ w_g1, fused with shfl colmax
    float s1[8];
#pragma unroll
    for (int j = 0; j < 8; j++) s1[j] = bg1[j];
#pragma unroll
    for (int i = 0; i < 64; i++) {
        float gi = (i < 32) ? gd[i] : pe[i - 32];
        float mx = gi;
        mx = fmaxf(mx, __shfl_xor(mx, 1));
        mx = fmaxf(mx, __shfl_xor(mx, 2));
        mx = fmaxf(mx, __shfl_xor(mx, 4));
        mx = fmaxf(mx, __shfl_xor(mx, 8));
        float sub = gi - mx;
#pragma unroll
        for (int j = 0; j < 8; j++) s1[j] += sub * wg1[i * 8 + j];
    }
#pragma unroll
    for (int j = 0; j < 8; j++) s1[j] = fmaxf(s1[j], 0.f);
    float s2[8];
#pragma unroll
    for (int j = 0; j < 8; j++) {
        float a = bg2[j];
#pragma unroll
        for (int i = 0; i < 8; i++) a += s1[i] * wg2[i * 8 + j];
        s2[j] = 1.f / (1.f + __expf(-a));    // sigmoid
    }
    // WeightNet: 12 -> 8 -> 8 -> 16 (relu each)
    float wa[8], wb[8];
#pragma unroll
    for (int j = 0; j < 8; j++) {
        float a = bn1[j];
#pragma unroll
        for (int i = 0; i < 12; i++) a += v[i] * wn1[i * 8 + j];
        wa[j] = fmaxf(a, 0.f);
    }
#pragma unroll
    for (int j = 0; j < 8; j++) {
        float a = bn2[j];
#pragma unroll
        for (int i = 0; i < 8; i++) a += wa[i] * wn2[i * 8 + j];
        wb[j] = fmaxf(a, 0.f);
    }
#pragma unroll
    for (int j = 0; j < 16; j++) {
        float a = bn3[j];
#pragma unroll
        for (int i = 0; i < 8; i++) a += wb[i] * wn3[i * 16 + j];
        U.a.w3[p][q][j] = fmaxf(a, 0.f);
    }
    // nf = gathered feats_x * head score
    {
        const float4* f4 = (const float4*)(fx + (long)ind * 32);
#pragma unroll
        for (int c8 = 0; c8 < 8; c8++) {
            float4 f = f4[c8];
            float s = s2[c8];               // head = channel/4 = c8
            float4 r;
            r.x = f.x * s; r.y = f.y * s; r.z = f.z * s; r.w = f.w * s;
            *(float4*)(&U.a.nf[p][q][c8 * 4]) = r;
        }
    }
    // shortcut max-pool: thread q owns channels [4q, 4q+4)
    {
        float4 mx = make_float4(-1e30f, -1e30f, -1e30f, -1e30f);
#pragma unroll
        for (int kk = 0; kk < 16; kk++) {
            int ik = sInd[p][kk];
            float4 d = *(const float4*)(df + (long)ik * 64 + q * 4);
            mx.x = fmaxf(mx.x, d.x); mx.y = fmaxf(mx.y, d.y);
            mx.z = fmaxf(mx.z, d.z); mx.w = fmaxf(mx.w, d.w);
        }
        *(float4*)(&sSf[p][q * 4]) = mx;
    }
    __syncthreads();

    // ---------------- phase 2: agg[c][j] = sum_k nf[k][c] * w3[k][j] --------
    // thread (p,q): j = q fixed, all 32 c in registers.
    float acc2[32];
#pragma unroll
    for (int c = 0; c < 32; c++) acc2[c] = 0.f;
#pragma unroll
    for (int kk = 0; kk < 16; kk++) {
        float w3v = U.a.w3[p][kk][q];
        const float* nfr = U.a.nf[p][kk];
#pragma unroll
        for (int c8 = 0; c8 < 8; c8++) {
            float4 f = *(const float4*)(nfr + c8 * 4);
            acc2[c8 * 4 + 0] += f.x * w3v;
            acc2[c8 * 4 + 1] += f.y * w3v;
            acc2[c8 * 4 + 2] += f.z * w3v;
            acc2[c8 * 4 + 3] += f.w * w3v;
        }
    }
    __syncthreads();   // all reads of U.a complete before union overwrite
#pragma unroll
    for (int c = 0; c < 32; c++) U.agg[p][c * 16 + q] = acc2[c];
    __syncthreads();

    // ---------------- phase 3: out64 = relu(agg @ w_lin + b_lin) ------------
    // wave wv handles p in {wv, wv+4, wv+8, wv+12}; lane l = output channel.
    {
        int wv = t >> 6, l = t & 63;
        float a0 = 0.f, a1 = 0.f, a2 = 0.f, a3 = 0.f;
        for (int i = 0; i < 512; i += 4) {
            float4 g0 = *(const float4*)(&U.agg[wv][i]);
            float4 g1 = *(const float4*)(&U.agg[wv + 4][i]);
            float4 g2 = *(const float4*)(&U.agg[wv + 8][i]);
            float4 g3 = *(const float4*)(&U.agg[wv + 12][i]);
            float w0 = wlin[(i + 0) * 64 + l];
            float w1v = wlin[(i + 1) * 64 + l];
            float w2v = wlin[(i + 2) * 64 + l];
            float w3v = wlin[(i + 3) * 64 + l];
            a0 += g0.x * w0 + g0.y * w1v + g0.z * w2v + g0.w * w3v;
            a1 += g1.x * w0 + g1.y * w1v + g1.z * w2v + g1.w * w3v;
            a2 += g2.x * w0 + g2.y * w1v + g2.z * w2v + g2.w * w3v;
            a3 += g3.x * w0 + g3.y * w1v + g3.z * w2v + g3.w * w3v;
        }
        float bl = blin[l];
        sOut64[wv][l]      = fmaxf(a0 + bl, 0.f);
        sOut64[wv + 4][l]  = fmaxf(a1 + bl, 0.f);
        sOut64[wv + 8][l]  = fmaxf(a2 + bl, 0.f);
        sOut64[wv + 12][l] = fmaxf(a3 + bl, 0.f);
    }
    __syncthreads();

    // ---------------- phase 4: out = leaky(out64@w_u2 + sf@w_sc + biases) ---
    {
        int c2 = t & 127;
        int pb = t >> 7;          // 0 or 1; p = pb + 2*pp
        float bb = bu2[c2] + bsc[c2];
        float acc[8];
#pragma unroll
        for (int pp = 0; pp < 8; pp++) acc[pp] = bb;
        for (int i = 0; i < 64; i += 4) {
            float u0 = wu2[(i + 0) * 128 + c2];
            float u1 = wu2[(i + 1) * 128 + c2];
            float u2v = wu2[(i + 2) * 128 + c2];
            float u3 = wu2[(i + 3) * 128 + c2];
#pragma unroll
            for (int pp = 0; pp < 8; pp++) {
                float4 o = *(const float4*)(&sOut64[pb + 2 * pp][i]);
                acc[pp] += o.x * u0 + o.y * u1 + o.z * u2v + o.w * u3;
            }
            float s0 = wsc[(i + 0) * 128 + c2];
            float s1v = wsc[(i + 1) * 128 + c2];
            float s2v = wsc[(i + 2) * 128 + c2];
            float s3 = wsc[(i + 3) * 128 + c2];
#pragma unroll
            for (int pp = 0; pp < 8; pp++) {
                float4 o = *(const float4*)(&sSf[pb + 2 * pp][i]);
                acc[pp] += o.x * s0 + o.y * s1v + o.z * s2v + o.w * s3;
            }
        }
        long mbase = (long)blockIdx.x * 16;
#pragma unroll
        for (int pp = 0; pp < 8; pp++) {
            long mm = mbase + pb + 2 * pp;
            if (mm < (long)M) {
                float x = acc[pp];
                out[mm * 128 + c2] = x > 0.f ? x : 0.1f * x;   // LeakyReLU(0.1)
            }
        }
    }
}

extern "C" void kernel_launch(void* const* d_in, const int* in_sizes, int n_in,
                              void* d_out, int out_size, void* d_ws, size_t ws_size,
                              hipStream_t stream)
{
    const float* dense_feats = (const float*)d_in[1];
    const float* vi    = (const float*)d_in[5];
    const int*   nei   = (const int*)d_in[6];
    const float* w_u1  = (const float*)d_in[7];
    const float* b_u1  = (const float*)d_in[8];
    const float* w_gu  = (const float*)d_in[9];
    const float* b_gu  = (const float*)d_in[10];
    const float* w_pe  = (const float*)d_in[11];
    const float* b_pe  = (const float*)d_in[12];
    const float* w_g1  = (const float*)d_in[13];
    const float* b_g1  = (const float*)d_in[14];
    const float* w_g2  = (const float*)d_in[15];
    const float* b_g2  = (const float*)d_in[16];
    const float* w_wn1 = (const float*)d_in[17];
    const float* b_wn1 = (const float*)d_in[18];
    const float* w_wn2 = (const float*)d_in[19];
    const float* b_wn2 = (const float*)d_in[20];
    const float* w_wn3 = (const float*)d_in[21];
    const float* b_wn3 = (const float*)d_in[22];
    const float* w_lin = (const float*)d_in[23];
    const float* b_lin = (const float*)d_in[24];
    const float* w_u2  = (const float*)d_in[25];
    const float* b_u2  = (const float*)d_in[26];
    const float* w_sc  = (const float*)d_in[27];
    const float* b_sc  = (const float*)d_in[28];

    int N = in_sizes[1] / 64;     // 200000
    int M = in_sizes[6] / 16;     // 100000

    float* fx  = (float*)d_ws;                 // [N,32]
    float* gxp = fx + (size_t)N * 32;          // [N,32]

    feats_kernel<<<(N + 7) / 8, 256, 0, stream>>>(
        dense_feats, w_u1, b_u1, w_gu, b_gu, fx, gxp, N);

    pcf_kernel<<<(M + 15) / 16, 256, 0, stream>>>(
        vi, nei, dense_feats, fx, gxp,
        w_pe, b_pe, w_g1, b_g1, w_g2, b_g2,
        w_wn1, b_wn1, w_wn2, b_wn2, w_wn3, b_wn3,
        w_lin, b_lin, w_u2, b_u2, w_sc, b_sc,
        (float*)d_out, M);
}

// Round 2
// 483.753 us; speedup vs baseline: 1.7419x; 1.7419x over previous
//
#include <hip/hip_runtime.h>
#include <math.h>

typedef __attribute__((ext_vector_type(8))) __bf16 bf16x8;
typedef __attribute__((ext_vector_type(4))) __bf16 bf16x4;
typedef __attribute__((ext_vector_type(4))) float f32x4;

// max over the 16-lane group via DPP row rotations (VALU, not LDS pipe)
__device__ __forceinline__ float rowmax16(float x) {
    int xi = __builtin_bit_cast(int, x);
    float y;
    y = __builtin_bit_cast(float, __builtin_amdgcn_update_dpp(0, xi, 0x128, 0xf, 0xf, true)); // ror:8
    x = fmaxf(x, y); xi = __builtin_bit_cast(int, x);
    y = __builtin_bit_cast(float, __builtin_amdgcn_update_dpp(0, xi, 0x124, 0xf, 0xf, true)); // ror:4
    x = fmaxf(x, y); xi = __builtin_bit_cast(int, x);
    y = __builtin_bit_cast(float, __builtin_amdgcn_update_dpp(0, xi, 0x122, 0xf, 0xf, true)); // ror:2
    x = fmaxf(x, y); xi = __builtin_bit_cast(int, x);
    y = __builtin_bit_cast(float, __builtin_amdgcn_update_dpp(0, xi, 0x121, 0xf, 0xf, true)); // ror:1
    x = fmaxf(x, y);
    return x;
}

// ---------------------------------------------------------------------------
// prep: transpose + bf16-cast the three epilogue weight matrices.
// wlinT[64][512] <- wlin[512][64]; wu2T[128][64] <- wu2[64][128]; wscT same.
// ---------------------------------------------------------------------------
__global__ void prep_kernel(const float* __restrict__ wlin,
                            const float* __restrict__ wu2,
                            const float* __restrict__ wsc,
                            __bf16* __restrict__ wlinT,
                            __bf16* __restrict__ wu2T,
                            __bf16* __restrict__ wscT)
{
    int i = blockIdx.x * 256 + threadIdx.x;
    if (i < 64 * 512) {
        int l = i >> 9, k = i & 511;
        wlinT[i] = (__bf16)wlin[k * 64 + l];
    } else if (i < 64 * 512 + 128 * 64) {
        int j = i - 64 * 512; int co = j >> 6, kk = j & 63;
        wu2T[j] = (__bf16)wu2[kk * 128 + co];
    } else if (i < 64 * 512 + 2 * 128 * 64) {
        int j = i - 64 * 512 - 128 * 64; int co = j >> 6, kk = j & 63;
        wscT[j] = (__bf16)wsc[kk * 128 + co];
    }
}

// ---------------------------------------------------------------------------
// Kernel A: feats_x / guidance_x. Grid-stride persistent blocks: stage the
// weights ONCE per block (round-1 version paid 12KB weight staging per 8 pts
// -> 300MB L2 traffic). 16 points per iteration.
// ---------------------------------------------------------------------------
__global__ __launch_bounds__(256) void feats_kernel(
    const float* __restrict__ df,
    const float* __restrict__ w1, const float* __restrict__ b1,
    const float* __restrict__ wg, const float* __restrict__ bg,
    float* __restrict__ fx, float* __restrict__ gx, int N)
{
    __shared__ float sW1[64][32];
    __shared__ float sWg[32][32];
    __shared__ float sIn[16][64];
    __shared__ float sFx[16][33];
    int t = threadIdx.x;
    for (int i = t; i < 64 * 32; i += 256) ((float*)sW1)[i] = w1[i];
    for (int i = t; i < 32 * 32; i += 256) ((float*)sWg)[i] = wg[i];
    int c = t & 31, pA = t >> 5, pB = pA + 8;
    int lp = t >> 4, lc4 = t & 15;
    float b1c = b1[c], bgc = bg[c];
    long ntiles = (N + 15) >> 4;
    for (long tile = blockIdx.x; tile < ntiles; tile += gridDim.x) {
        long n0 = tile * 16;
        __syncthreads();                      // previous iteration readers done
        long nl = n0 + lp;
        if (nl < N)
            *(float4*)(&sIn[lp][lc4 * 4]) = *(const float4*)(df + nl * 64 + lc4 * 4);
        __syncthreads();
        float a0 = b1c, a1 = b1c;
#pragma unroll
        for (int i = 0; i < 64; i++) {
            a0 += sIn[pA][i] * sW1[i][c];
            a1 += sIn[pB][i] * sW1[i][c];
        }
        a0 = a0 > 0.f ? a0 : 0.1f * a0;
        a1 = a1 > 0.f ? a1 : 0.1f * a1;
        sFx[pA][c] = a0; sFx[pB][c] = a1;
        __syncthreads();
        float g0 = bgc, g1 = bgc;
#pragma unroll
        for (int i = 0; i < 32; i++) {
            g0 += sFx[pA][i] * sWg[i][c];
            g1 += sFx[pB][i] * sWg[i][c];
        }
        long nA = n0 + pA, nB = n0 + pB;
        if (nA < N) { fx[nA * 32 + c] = a0; gx[nA * 32 + c] = g0; }
        if (nB < N) { fx[nB * 32 + c] = a1; gx[nB * 32 + c] = g1; }
    }
}

// ---------------------------------------------------------------------------
// Kernel B: 16 sparse points / 256-thread block.
// phase1: per-(p,q) fp32 VALU pipeline -> nf(bf16), w3(bf16), sf(bf16) in LDS
// phase2: agg[p][512] (fp32 accum) -> bf16 LDS, k-contiguous per thread
// phase3: MFMA 16x16x32 bf16: out64 = relu(agg @ wlinT^T + blin)
// phase4: MFMA: out = leaky(out64 @ wu2 + sf @ wsc + b)
// LDS total 38400 B -> 4 blocks/CU.
// ---------------------------------------------------------------------------
struct SmemU {
    union {
        struct { __bf16 nfb[16][16][40]; __bf16 w3b[16][16][24]; } a; // 32768 B
        __bf16 aggB[16][520];                                         // 16640 B
    };
};

__global__ __launch_bounds__(256, 4) void pcf_kernel(
    const float* __restrict__ vi, const int* __restrict__ nei,
    const float* __restrict__ df,
    const float* __restrict__ fx, const float* __restrict__ gx,
    const float* __restrict__ wpe, const float* __restrict__ bpe,
    const float* __restrict__ wg1, const float* __restrict__ bg1,
    const float* __restrict__ wg2, const float* __restrict__ bg2,
    const float* __restrict__ wn1, const float* __restrict__ bn1,
    const float* __restrict__ wn2, const float* __restrict__ bn2,
    const float* __restrict__ wn3, const float* __restrict__ bn3,
    const __bf16* __restrict__ wlinT, const float* __restrict__ blin,
    const __bf16* __restrict__ wu2T, const float* __restrict__ bu2,
    const __bf16* __restrict__ wscT, const float* __restrict__ bsc,
    float* __restrict__ out, int M)
{
    __shared__ SmemU U;
    __shared__ __bf16 sO[16][72];     // out64, padded rows (144B)
    __shared__ __bf16 sS[16][72];     // shortcut maxpool
    __shared__ int sInd[16][16];

    int t = threadIdx.x;
    int p = t >> 4, q = t & 15;
    long m = (long)blockIdx.x * 16 + p;
    bool okm = m < (long)M;
    int ind = okm ? nei[m * 16 + q] : 0;
    sInd[p][q] = ind;                 // consumed within the same wave only

    // ---------------- phase 1 ----------------
    float v[12];
    {
        const float4* v4 = (const float4*)(vi + (okm ? (m * 16 + q) * 12 : 0));
        float4 a = v4[0], b = v4[1], cc = v4[2];
        v[0] = a.x; v[1] = a.y; v[2] = a.z; v[3] = a.w;
        v[4] = b.x; v[5] = b.y; v[6] = b.z; v[7] = b.w;
        v[8] = cc.x; v[9] = cc.y; v[10] = cc.z; v[11] = cc.w;
    }
    float pe[32];
#pragma unroll
    for (int c = 0; c < 32; c++) {
        float a = bpe[c];
#pragma unroll
        for (int i = 0; i < 12; i++) a += v[i] * wpe[i * 32 + c];
        pe[c] = fmaxf(a, 0.f);
    }
    float gd[32];
    {
        const float4* g4 = (const float4*)(gx + (long)ind * 32);
#pragma unroll
        for (int c8 = 0; c8 < 8; c8++) {
            float4 gg = g4[c8];
            gd[c8 * 4 + 0] = gg.x; gd[c8 * 4 + 1] = gg.y;
            gd[c8 * 4 + 2] = gg.z; gd[c8 * 4 + 3] = gg.w;
        }
    }
    float s1[8];
#pragma unroll
    for (int j = 0; j < 8; j++) s1[j] = bg1[j];
#pragma unroll
    for (int i = 0; i < 64; i++) {
        float gi = (i < 32) ? gd[i] : pe[i - 32];
        float sub = gi - rowmax16(gi);
#pragma unroll
        for (int j = 0; j < 8; j++) s1[j] += sub * wg1[i * 8 + j];
    }
#pragma unroll
    for (int j = 0; j < 8; j++) s1[j] = fmaxf(s1[j], 0.f);
    float s2[8];
#pragma unroll
    for (int j = 0; j < 8; j++) {
        float a = bg2[j];
#pragma unroll
        for (int i = 0; i < 8; i++) a += s1[i] * wg2[i * 8 + j];
        s2[j] = 1.f / (1.f + __expf(-a));
    }
    float wa[8], wb[8];
#pragma unroll
    for (int j = 0; j < 8; j++) {
        float a = bn1[j];
#pragma unroll
        for (int i = 0; i < 12; i++) a += v[i] * wn1[i * 8 + j];
        wa[j] = fmaxf(a, 0.f);
    }
#pragma unroll
    for (int j = 0; j < 8; j++) {
        float a = bn2[j];
#pragma unroll
        for (int i = 0; i < 8; i++) a += wa[i] * wn2[i * 8 + j];
        wb[j] = fmaxf(a, 0.f);
    }
    {
        float w3v[16];
#pragma unroll
        for (int j = 0; j < 16; j++) {
            float a = bn3[j];
#pragma unroll
            for (int i = 0; i < 8; i++) a += wb[i] * wn3[i * 16 + j];
            w3v[j] = fmaxf(a, 0.f);
        }
        bf16x8 wlo, whi;
#pragma unroll
        for (int jj = 0; jj < 8; jj++) { wlo[jj] = (__bf16)w3v[jj]; whi[jj] = (__bf16)w3v[8 + jj]; }
        *(bf16x8*)(&U.a.w3b[p][q][0]) = wlo;
        *(bf16x8*)(&U.a.w3b[p][q][8]) = whi;
    }
    {
        const float4* f4 = (const float4*)(fx + (long)ind * 32);
        float nfv[32];
#pragma unroll
        for (int c8 = 0; c8 < 8; c8++) {
            float4 f = f4[c8];
            float s = s2[c8];
            nfv[c8 * 4 + 0] = f.x * s; nfv[c8 * 4 + 1] = f.y * s;
            nfv[c8 * 4 + 2] = f.z * s; nfv[c8 * 4 + 3] = f.w * s;
        }
#pragma unroll
        for (int g = 0; g < 4; g++) {
            bf16x8 pk;
#pragma unroll
            for (int e = 0; e < 8; e++) pk[e] = (__bf16)nfv[g * 8 + e];
            *(bf16x8*)(&U.a.nfb[p][q][g * 8]) = pk;
        }
    }
    {
        float4 mx = make_float4(-1e30f, -1e30f, -1e30f, -1e30f);
#pragma unroll
        for (int kk = 0; kk < 16; kk++) {
            int ik = sInd[p][kk];
            float4 d = *(const float4*)(df + (long)ik * 64 + q * 4);
            mx.x = fmaxf(mx.x, d.x); mx.y = fmaxf(mx.y, d.y);
            mx.z = fmaxf(mx.z, d.z); mx.w = fmaxf(mx.w, d.w);
        }
        bf16x4 pk;
        pk[0] = (__bf16)mx.x; pk[1] = (__bf16)mx.y; pk[2] = (__bf16)mx.z; pk[3] = (__bf16)mx.w;
        *(bf16x4*)(&sS[p][q * 4]) = pk;
    }
    __syncthreads();

    // ---------------- phase 2: agg[p][k], k = c*16 + j ----------------
    // thread (p,q) owns k in { c4*128 + q*8 .. +8 } for c4=0..3
    {
        int chalf = q >> 1, j0 = (q & 1) * 8;
        float acc[4][8];
#pragma unroll
        for (int c4 = 0; c4 < 4; c4++)
#pragma unroll
            for (int j = 0; j < 8; j++) acc[c4][j] = 0.f;
#pragma unroll
        for (int kk = 0; kk < 16; kk++) {
            bf16x8 w8 = *(const bf16x8*)(&U.a.w3b[p][kk][j0]);
            float wf[8];
#pragma unroll
            for (int e = 0; e < 8; e++) wf[e] = (float)w8[e];
#pragma unroll
            for (int c4 = 0; c4 < 4; c4++) {
                float nfc = (float)U.a.nfb[p][kk][c4 * 8 + chalf];
#pragma unroll
                for (int j = 0; j < 8; j++) acc[c4][j] += nfc * wf[j];
            }
        }
        __syncthreads();          // all union-a reads complete before overwrite
#pragma unroll
        for (int c4 = 0; c4 < 4; c4++) {
            bf16x8 pk;
#pragma unroll
            for (int j = 0; j < 8; j++) pk[j] = (__bf16)acc[c4][j];
            *(bf16x8*)(&U.aggB[p][c4 * 128 + q * 8]) = pk;
        }
    }
    __syncthreads();

    // ---------------- phase 3: out64 = relu(agg @ wlin + blin), MFMA --------
    // wave wv -> l-tile [16wv,16wv+16). A[m][k]=aggB[m][k]; B from wlinT rows.
    {
        int wv = t >> 6, ln = t & 63;
        int n = ln & 15, quad = ln >> 4;
        f32x4 acc = {0.f, 0.f, 0.f, 0.f};
        const __bf16* Bp = wlinT + ((wv * 16 + n) * 512 + quad * 8);
#pragma unroll
        for (int kk = 0; kk < 16; kk++) {
            bf16x8 af = *(const bf16x8*)(&U.aggB[n][0] + 0);  // placeholder avoided below
            (void)af;
            break;
        }
        // real loop (A row = lane&15 as m)
        acc = (f32x4){0.f, 0.f, 0.f, 0.f};
#pragma unroll
        for (int kk = 0; kk < 16; kk++) {
            bf16x8 a = *(const bf16x8*)(&U.aggB[n][kk * 32 + quad * 8]);
            bf16x8 b = *(const bf16x8*)(Bp + kk * 32);
            acc = __builtin_amdgcn_mfma_f32_16x16x32_bf16(a, b, acc, 0, 0, 0);
        }
        int col = wv * 16 + n;
        float bl = blin[col];
#pragma unroll
        for (int r = 0; r < 4; r++) {
            int row = quad * 4 + r;
            sO[row][col] = (__bf16)fmaxf(acc[r] + bl, 0.f);
        }
    }
    __syncthreads();

    // ---------------- phase 4: out = leaky(out64@wu2 + sf@wsc + b), MFMA ----
    {
        int wv = t >> 6, ln = t & 63;
        int n = ln & 15, quad = ln >> 4;
        bf16x8 aO0 = *(const bf16x8*)(&sO[n][quad * 8]);
        bf16x8 aO1 = *(const bf16x8*)(&sO[n][32 + quad * 8]);
        bf16x8 aS0 = *(const bf16x8*)(&sS[n][quad * 8]);
        bf16x8 aS1 = *(const bf16x8*)(&sS[n][32 + quad * 8]);
        long mbase = (long)blockIdx.x * 16;
#pragma unroll
        for (int tt = 0; tt < 2; tt++) {
            int T = wv * 2 + tt;
            int col = T * 16 + n;
            const __bf16* B1 = wu2T + (col * 64 + quad * 8);
            const __bf16* B2 = wscT + (col * 64 + quad * 8);
            f32x4 acc = {0.f, 0.f, 0.f, 0.f};
            acc = __builtin_amdgcn_mfma_f32_16x16x32_bf16(aO0, *(const bf16x8*)(B1), acc, 0, 0, 0);
            acc = __builtin_amdgcn_mfma_f32_16x16x32_bf16(aO1, *(const bf16x8*)(B1 + 32), acc, 0, 0, 0);
            acc = __builtin_amdgcn_mfma_f32_16x16x32_bf16(aS0, *(const bf16x8*)(B2), acc, 0, 0, 0);
            acc = __builtin_amdgcn_mfma_f32_16x16x32_bf16(aS1, *(const bf16x8*)(B2 + 32), acc, 0, 0, 0);
            float bb = bu2[col] + bsc[col];
#pragma unroll
            for (int r = 0; r < 4; r++) {
                long mm = mbase + quad * 4 + r;
                if (mm < (long)M) {
                    float x = acc[r] + bb;
                    out[mm * 128 + col] = x > 0.f ? x : 0.1f * x;
                }
            }
        }
    }
}

extern "C" void kernel_launch(void* const* d_in, const int* in_sizes, int n_in,
                              void* d_out, int out_size, void* d_ws, size_t ws_size,
                              hipStream_t stream)
{
    const float* dense_feats = (const float*)d_in[1];
    const float* vi    = (const float*)d_in[5];
    const int*   nei   = (const int*)d_in[6];
    const float* w_u1  = (const float*)d_in[7];
    const float* b_u1  = (const float*)d_in[8];
    const float* w_gu  = (const float*)d_in[9];
    const float* b_gu  = (const float*)d_in[10];
    const float* w_pe  = (const float*)d_in[11];
    const float* b_pe  = (const float*)d_in[12];
    const float* w_g1  = (const float*)d_in[13];
    const float* b_g1  = (const float*)d_in[14];
    const float* w_g2  = (const float*)d_in[15];
    const float* b_g2  = (const float*)d_in[16];
    const float* w_wn1 = (const float*)d_in[17];
    const float* b_wn1 = (const float*)d_in[18];
    const float* w_wn2 = (const float*)d_in[19];
    const float* b_wn2 = (const float*)d_in[20];
    const float* w_wn3 = (const float*)d_in[21];
    const float* b_wn3 = (const float*)d_in[22];
    const float* w_lin = (const float*)d_in[23];
    const float* b_lin = (const float*)d_in[24];
    const float* w_u2  = (const float*)d_in[25];
    const float* b_u2  = (const float*)d_in[26];
    const float* w_sc  = (const float*)d_in[27];
    const float* b_sc  = (const float*)d_in[28];

    int N = in_sizes[1] / 64;     // 200000
    int M = in_sizes[6] / 16;     // 100000

    float* fx  = (float*)d_ws;                    // [N,32] f32
    float* gxp = fx + (size_t)N * 32;             // [N,32] f32
    __bf16* wlinT = (__bf16*)(gxp + (size_t)N * 32);  // [64,512]
    __bf16* wu2T  = wlinT + 64 * 512;                  // [128,64]
    __bf16* wscT  = wu2T + 128 * 64;                   // [128,64]

    prep_kernel<<<(64 * 512 + 2 * 128 * 64 + 255) / 256, 256, 0, stream>>>(
        w_lin, w_u2, w_sc, wlinT, wu2T, wscT);

    feats_kernel<<<1024, 256, 0, stream>>>(
        dense_feats, w_u1, b_u1, w_gu, b_gu, fx, gxp, N);

    pcf_kernel<<<(M + 15) / 16, 256, 0, stream>>>(
        vi, nei, dense_feats, fx, gxp,
        w_pe, b_pe, w_g1, b_g1, w_g2, b_g2,
        w_wn1, b_wn1, w_wn2, b_wn2, w_wn3, b_wn3,
        wlinT, b_lin, wu2T, b_u2, wscT, b_sc,
        (float*)d_out, M);
}